// Round 8
// baseline (134.470 us; speedup 1.0000x reference)
//
#include <hip/hip_runtime.h>
#include <utility>

// EquivariantProductBasisBlock (MACE-style) for gfx950 — round 19.
// R18 post-mortem: GEMM-tiled linear had 256 blocks = 1 block/CU = 1
// wave/SIMD -> no latency hiding + LDS-pipe serialization; total 106.2
// (worse than R12's 100.1). Cross-round insight: EVERY linear variant was
// BW/LDS-bound because each wave privately streamed operands (1KB per
// wave-instr). Fix = LANE ADDRESS SHARING: wave = 16 nodes x 4 f-quads ->
// W-load has 4 distinct 16B addrs/wave (16-way shared, 128B/instr), B-load
// 16 distinct (4-way, 256B/instr). ~8x less traffic; W f-chunk (32KB)
// L1-resident and reused across a CU's blocks (node-major bid: fc = bid&3
// constant per CU since 1024 blocks / 256 CUs strides by 256, 256%4==0).
// No LDS, no barrier; VGPR ~50-64. VALU floor 3.4us -> predict 5-7us.
// R19 = R18 basis (unchanged) + lane-shared linear. Predict dur 88-94.

#define NN 4096
#define NC 128
#define NE 10

typedef float v2f __attribute__((ext_vector_type(2)));

__device__ __forceinline__ v2f ld2(const float* p) {
  return *reinterpret_cast<const v2f*>(p);
}
__device__ __forceinline__ v2f cfma(float c, v2f x, v2f a) {  // a += c*x (splat c)
  v2f cc = {c, c};
  return __builtin_elementwise_fma(cc, x, a);
}
__device__ __forceinline__ v2f vfma(v2f w, v2f x, v2f a) {    // a += w*x
  return __builtin_elementwise_fma(w, x, a);
}

// ---------------------------- static_for ---------------------------------------
template<typename F, int... Is>
__device__ __forceinline__ void sfor_impl(F&& f, std::integer_sequence<int, Is...>) {
  (f(std::integral_constant<int, Is>{}), ...);
}
template<int N, typename F>
__device__ __forceinline__ void sfor(F&& f) {
  sfor_impl((F&&)f, std::make_integer_sequence<int, N>{});
}

// ---------------------------- CG metadata (constexpr) --------------------------
constexpr int T_L1c[19]  = {0,0,0,1,1,1,1,1,1,1,2,2,2,2,2,2,2,2,3};
constexpr int T_L2c[19]  = {0,1,2,0,1,1,1,2,2,2,0,1,1,1,2,2,2,2,2};
constexpr int T_L3c[19]  = {0,1,2,1,0,1,2,1,2,3,2,1,2,3,0,1,2,3,1};
constexpr int T_OFFc[19] = {0,1,10,35,44,53,80,125,170,245,350,375,420,495,600,625,700,825,1000};
constexpr int AOFFc[3]   = {0,1,4};

constexpr int P2U_L1c[7]  = {0,0,1,1,1,2,2};
constexpr int P2U_L2c[7]  = {0,1,1,1,2,2,2};
constexpr int P2U_LOc[7]  = {0,1,0,1,1,0,1};
constexpr int P2U_TBLc[7] = {0,1,4,5,7,14,15};
constexpr int P2U_WAc[7]  = {0,1,3,4,5,7,8};
constexpr int P2U_WBc[7]  = {-1,2,-1,-1,6,-1,-1};

constexpr int K_L1c[18]  = {0,0,0,1,1,1,1,1,1,1,2,2,2,2,2,2,2,2};
constexpr int K_L2c[18]  = {0,1,2,0,1,1,1,2,2,2,0,1,1,1,2,2,2,2};
constexpr int K_L12c[18] = {0,1,2,1,0,1,2,1,2,3,2,1,2,3,0,1,2,3};

constexpr int   TT_CANONc[18] = {0,1,2,1,4,5,6,7,8,9,2,7,8,9,14,15,16,17};
constexpr float TT_SGNc[18]   = {1,1,1,1,1,1,1,1,1,1,1,1,-1,1,1,1,1,1};
constexpr int CANONc[13] = {0,1,2,4,5,6,7,8,9,14,15,16,17};
constexpr int CONS2c[13] = {-1,3,10,-1,-1,-1,11,12,13,-1,-1,-1,-1};

constexpr int P3_STARTc[19] = {0,2,6,9,13,15,19,22,26,29,30,33,37,40,41,43,47,50,51};
constexpr int P3_L3c[51] = {
  0,1,  0,1,1,2,  1,2,2,  0,1,1,2,  0,1,  0,1,1,2,  1,2,2,  0,1,1,2,  1,2,2,
  2,  1,2,2,  0,1,1,2,  1,2,2,  2,  0,1,  0,1,1,2,  1,2,2,  2 };
constexpr int P3_LOc[51] = {
  0,1,  1,0,1,1,  1,0,1,  1,0,1,1,  0,1,  1,0,1,1,  1,0,1,  1,0,1,1,  1,0,1,
  1,  1,0,1,  1,0,1,1,  1,0,1,  1,  0,1,  1,0,1,1,  1,0,1,  1 };
constexpr int P3_TBLc[51] = {
  0,1,  3,4,5,7,  11,14,15,  3,4,5,7,  0,1,  3,4,5,7,  11,14,15,  3,4,5,7,
  11,14,15,  18,  11,14,15,  3,4,5,7,  11,14,15,  18,  0,1,  3,4,5,7,
  11,14,15,  18 };

// ---------------------------- constexpr CG computation -------------------------
constexpr double cfact(int n) { double r = 1.0; for (int i = 2; i <= n; ++i) r *= i; return r; }
constexpr double csqrt(double x) {
  if (x <= 0.0) return 0.0;
  double r = x > 1.0 ? x : 1.0;
  for (int i = 0; i < 64; ++i) r = 0.5 * (r + x / r);
  return r;
}
constexpr double su2cg(int j1, int m1, int j2, int m2, int j3, int m3) {
  if (m3 != m1 + m2) return 0.0;
  int vmin = -j1 + j2 + m3; if (-j1 + m1 > vmin) vmin = -j1 + m1; if (vmin < 0) vmin = 0;
  int vmax = j2 + j3 + m1; if (j3 - j1 + j2 < vmax) vmax = j3 - j1 + j2; if (j3 + m3 < vmax) vmax = j3 + m3;
  double C = csqrt((2.0 * j3 + 1.0)
                   * cfact(j3 + j1 - j2) * cfact(j3 - j1 + j2) * cfact(j1 + j2 - j3)
                   * cfact(j3 + m3) * cfact(j3 - m3)
                   / (cfact(j1 + j2 + j3 + 1) * cfact(j1 - m1) * cfact(j1 + m1)
                      * cfact(j2 - m2) * cfact(j2 + m2)));
  double S = 0.0;
  for (int v = vmin; v <= vmax; ++v) {
    double sgn = ((v + j2 + m2) & 1) ? -1.0 : 1.0;
    S += sgn * cfact(j2 + j3 + m1 - v) * cfact(j1 - m1 + v)
         / (cfact(v) * cfact(j3 - j1 + j2 - v) * cfact(j3 + m3 - v) * cfact(v + j1 - j2 - m3));
  }
  return C * S;
}

struct Cx { double re, im; };
constexpr Cx cxmul(Cx a, Cx b) { return Cx{a.re * b.re - a.im * b.im, a.re * b.im + a.im * b.re}; }
struct Row { int cnt; int col[2]; Cx v[2]; };

constexpr Row c2r_row(int l, int r) {
  Row out{0, {0, 0}, {{0, 0}, {0, 0}}};
  constexpr double is2 = 0.70710678118654752440;
  const int m = r - l;
  if (m < 0) {
    out.cnt = 2;
    out.col[0] = l - m; out.v[0] = Cx{is2, 0.0};
    out.col[1] = l + m; out.v[1] = Cx{0.0, -is2};
  } else if (m == 0) {
    out.cnt = 1; out.col[0] = l; out.v[0] = Cx{1.0, 0.0};
  } else {
    const double sgn = (m & 1) ? -1.0 : 1.0;
    out.cnt = 2;
    out.col[0] = l + m; out.v[0] = Cx{sgn * is2, 0.0};
    out.col[1] = l - m; out.v[1] = Cx{0.0, sgn * is2};
  }
  const int ph = l & 3;
  for (int a = 0; a < out.cnt; ++a) {
    Cx v = out.v[a];
    out.v[a] = (ph == 0) ? v
             : (ph == 1) ? Cx{v.im, -v.re}
             : (ph == 2) ? Cx{-v.re, -v.im}
                         : Cx{-v.im, v.re};
  }
  return out;
}

struct CGAll { float v[1105]; };
constexpr CGAll make_cg() {
  CGAll R{};
  for (int t = 0; t < 19; ++t) {
    const int l1 = T_L1c[t], l2 = T_L2c[t], l3 = T_L3c[t], off = T_OFFc[t];
    const int d1 = 2 * l1 + 1, d2 = 2 * l2 + 1, d3 = 2 * l3 + 1;
    double tmp[175] = {};
    for (int i = 0; i < d1; ++i) {
      const int m1 = i - l1;
      const Row r1 = c2r_row(l1, i);
      for (int k = 0; k < d2; ++k) {
        const int m2 = k - l2, m3 = m1 + m2;
        if (m3 < -l3 || m3 > l3) continue;
        const double cc = su2cg(l1, m1, l2, m2, l3, m3);
        if (cc == 0.0) continue;
        const Row r2 = c2r_row(l2, k);
        const Row r3 = c2r_row(l3, m3 + l3);
        for (int a = 0; a < r1.cnt; ++a)
          for (int b = 0; b < r2.cnt; ++b) {
            const Cx q12 = cxmul(r1.v[a], r2.v[b]);
            for (int cdx = 0; cdx < r3.cnt; ++cdx) {
              const double re = q12.re * r3.v[cdx].re + q12.im * r3.v[cdx].im;
              tmp[(r1.col[a] * d2 + r2.col[b]) * d3 + r3.col[cdx]] += re * cc;
            }
          }
      }
    }
    const int sz = d1 * d2 * d3;
    for (int e = 0; e < sz; ++e) R.v[off + e] = (float)tmp[e];
  }
  return R;
}
constexpr CGAll CG_ALL = make_cg();

constexpr bool check_cg_sym() {
  for (int t = 0; t < 18; ++t) {
    const int tc = TT_CANONc[t];
    if (tc == t) continue;
    const int l1 = K_L1c[t], l2 = K_L2c[t], l12 = K_L12c[t];
    const int d1 = 2*l1+1, d2 = 2*l2+1, d12 = 2*l12+1;
    for (int i = 0; i < d1; ++i)
      for (int j = 0; j < d2; ++j)
        for (int k = 0; k < d12; ++k) {
          float a = CG_ALL.v[T_OFFc[t]  + (i*d2 + j)*d12 + k];
          float b = TT_SGNc[t] * CG_ALL.v[T_OFFc[tc] + (j*d1 + i)*d12 + k];
          float d = a - b; if (d < 0) d = -d;
          if (d > 1e-5f) return false;
        }
  }
  return true;
}
static_assert(check_cg_sym(), "CG exchange symmetry violated");

// ============================ basis kernel (exact R9/R11 form) =================
__global__ __launch_bounds__(256) void epb_basis(
    const float* __restrict__ nf,      // [N, C, 9]
    const float* __restrict__ w1,      // [E, 2, C]
    const float* __restrict__ w2,      // [E, 9, C]
    const float* __restrict__ w3,      // [E, 51, C]
    const int*   __restrict__ species, // [N]
    float4* __restrict__ Bws)          // [N, C]
{
  const int t  = threadIdx.x;
  const int nb = blockIdx.x * 4;
  const int nl = t >> 6;               // wave-uniform node
  const int c0 = (t & 63) * 2;         // channel pair
  const int n  = nb + nl;
  const int s  = species[n];

  const float* ap = nf + ((size_t)n * NC + c0) * 9;
  v2f A[9];
  sfor<9>([&](auto I) { A[I.value] = v2f{ap[I.value], ap[I.value + 9]}; });

  const float* w1p = w1 + (size_t)s * 2  * NC + c0;
  const float* w2p = w2 + (size_t)s * 9  * NC + c0;
  const float* w3p = w3 + (size_t)s * 51 * NC + c0;

  v2f B[4];
  {
    const v2f wa = ld2(w1p), wb = ld2(w1p + NC);
    B[0] = wa * A[0];
    B[1] = wb * A[1];
    B[2] = wb * A[2];
    B[3] = wb * A[3];
  }

  sfor<7>([&](auto P) {
    constexpr int p  = P.value;
    constexpr int l1 = P2U_L1c[p], l2 = P2U_L2c[p], lo = P2U_LOc[p];
    constexpr int d1 = 2*l1+1, d2 = 2*l2+1, dl = 2*lo+1;
    constexpr int off = T_OFFc[P2U_TBLc[p]];
    v2f w = ld2(w2p + P2U_WAc[p] * NC);
    if constexpr (P2U_WBc[p] >= 0) w = w + ld2(w2p + P2U_WBc[p] * NC);
    sfor<dl>([&](auto Kk) {
      constexpr int k = Kk.value;
      v2f v = {0.f, 0.f};
      sfor<d1>([&](auto I) {
        sfor<d2>([&](auto J) {
          constexpr float cgc = CG_ALL.v[off + (I.value * d2 + J.value) * dl + k];
          if constexpr (cgc != 0.0f) {
            constexpr int ia = AOFFc[l1] + I.value, ja = AOFFc[l2] + J.value;
            constexpr int x = ia < ja ? ia : ja, y = ia < ja ? ja : ia;
            v = cfma(cgc, A[x] * A[y], v);
          }
        });
      });
      B[lo + k] = vfma(w, v, B[lo + k]);
    });
  });

  sfor<13>([&](auto CI) {
    constexpr int tk  = CANONc[CI.value];
    constexpr int l1  = K_L1c[tk], l2 = K_L2c[tk], l12 = K_L12c[tk];
    constexpr int d1  = 2*l1+1, d2 = 2*l2+1, d12 = 2*l12+1;
    constexpr int off = T_OFFc[tk];
    v2f tt[d12];
    sfor<d12>([&](auto Kk) {
      constexpr int k = Kk.value;
      v2f v = {0.f, 0.f};
      sfor<d1>([&](auto I) {
        sfor<d2>([&](auto J) {
          constexpr float cgc = CG_ALL.v[off + (I.value * d2 + J.value) * d12 + k];
          if constexpr (cgc != 0.0f) {
            constexpr int ia = AOFFc[l1] + I.value, ja = AOFFc[l2] + J.value;
            constexpr int x = ia < ja ? ia : ja, y = ia < ja ? ja : ia;
            v = cfma(cgc, A[x] * A[y], v);
          }
        });
      });
      tt[k] = v;
    });

    auto consume = [&](auto TK, auto SG) {
      constexpr int tkey = TK.value;
      constexpr float sgn = (float)SG.value;
      constexpr int pcnt = P3_STARTc[tkey + 1] - P3_STARTc[tkey];
      sfor<pcnt>([&](auto PP) {
        constexpr int p  = P3_STARTc[tkey] + PP.value;
        constexpr int l3 = P3_L3c[p], lo = P3_LOc[p];
        constexpr int d3 = 2*l3+1, dl = 2*lo+1;
        constexpr int off2 = T_OFFc[P3_TBLc[p]];
        const v2f w = ld2(w3p + p * NC);
        sfor<dl>([&](auto M) {
          v2f v = {0.f, 0.f};
          sfor<d12>([&](auto Kk) {
            sfor<d3>([&](auto J) {
              constexpr float cgc = sgn * CG_ALL.v[off2 + (Kk.value * d3 + J.value) * dl + M.value];
              if constexpr (cgc != 0.0f)
                v = cfma(cgc, tt[Kk.value] * A[AOFFc[l3] + J.value], v);
            });
          });
          B[lo + M.value] = vfma(w, v, B[lo + M.value]);
        });
      });
    };
    consume(std::integral_constant<int, tk>{}, std::integral_constant<int, 1>{});
    constexpr int td = CONS2c[CI.value];
    if constexpr (td >= 0)
      consume(std::integral_constant<int, td>{},
              std::integral_constant<int, (int)TT_SGNc[td]>{});
  });

  Bws[(size_t)n * NC + c0]     = make_float4(B[0].x, B[1].x, B[2].x, B[3].x);
  Bws[(size_t)n * NC + c0 + 1] = make_float4(B[0].y, B[1].y, B[2].y, B[3].y);
}

// ============================ linear kernel (lane-shared, no LDS) ==============
// 1024 blocks x 256 thr. Block = 16 nodes x 32 features (f-chunk fc).
// bid: fc = bid & 3 (node-major -> each CU keeps ONE fc; W chunk 32KB stays
// L1-resident across its blocks), nchunk = bid >> 2.
// Thread = (nl = t&15, fq = (t>>4)&7, h = t>>7). Wave = 16 nl x 4 fq:
//   W-load: 4 distinct 16B addrs (16-way lane-share) = 64B/instr
//   B-load: 16 distinct 16B addrs (4-way share, 4 lines) -> L1-hot
// acc = 4f x 4m = 16 VGPR; 64 c-iters x 16 FMA. No LDS, no barrier.
__global__ __launch_bounds__(256) void epb_linear(
    const float4* __restrict__ Bws,    // [N, C]
    const float4* __restrict__ lw0_4,  // [C, F/4]
    const float4* __restrict__ lw1_4,  // [C, F/4]
    float* __restrict__ out)           // [N, F, 4]
{
  const int t  = threadIdx.x;
  const int fc = blockIdx.x & 3;
  const int nb = (blockIdx.x >> 2) * 16;

  const int nl = t & 15;
  const int fq = (t >> 4) & 7;         // f-quad within chunk
  const int h  = t >> 7;               // channel half

  const int n  = nb + nl;
  const int fquad = fc * 8 + fq;       // global f-quad 0..31

  const float4* bp  = Bws + (size_t)n * NC + h * 64;
  const float4* w0c = lw0_4 + (size_t)(h * 64) * 32 + fquad;
  const float4* w1c = lw1_4 + (size_t)(h * 64) * 32 + fquad;

  float4 acc[4] = {};                  // [f_local], comps = m 0..3

  #pragma unroll 4
  for (int i = 0; i < 64; ++i) {
    const float4 b  = bp[i];           // 16 distinct addrs/wave (4-way share)
    const float4 wa = w0c[i * 32];     // 4 distinct addrs/wave (16-way share)
    const float4 wb = w1c[i * 32];
    acc[0].x = fmaf(b.x, wa.x, acc[0].x); acc[0].y = fmaf(b.y, wb.x, acc[0].y);
    acc[0].z = fmaf(b.z, wb.x, acc[0].z); acc[0].w = fmaf(b.w, wb.x, acc[0].w);
    acc[1].x = fmaf(b.x, wa.y, acc[1].x); acc[1].y = fmaf(b.y, wb.y, acc[1].y);
    acc[1].z = fmaf(b.z, wb.y, acc[1].z); acc[1].w = fmaf(b.w, wb.y, acc[1].w);
    acc[2].x = fmaf(b.x, wa.z, acc[2].x); acc[2].y = fmaf(b.y, wb.z, acc[2].y);
    acc[2].z = fmaf(b.z, wb.z, acc[2].z); acc[2].w = fmaf(b.w, wb.z, acc[2].w);
    acc[3].x = fmaf(b.x, wa.w, acc[3].x); acc[3].y = fmaf(b.y, wb.w, acc[3].y);
    acc[3].z = fmaf(b.z, wb.w, acc[3].z); acc[3].w = fmaf(b.w, wb.w, acc[3].w);
  }

  // cross-half reduction: partner thread t^128 holds the other 64 channels.
  // Same wave? No — t and t^128 are in different waves. Use global atomic-free
  // path instead: halves write disjoint scratch? Simpler: shfl won't reach.
  // -> Use LDS-free approach: halves combine via __shfl across waves is not
  //    possible; instead store partials to a small LDS buffer (4KB) once.
  __shared__ float4 Red[256 * 4];      // 16 KB: [t][f_local]
  sfor<4>([&](auto F_) { Red[(t & 127) * 4 + F_.value + (t >> 7) * 512] = acc[F_.value]; });
  __syncthreads();
  if (h == 0) {
    const float s4 = 0.08838834764831845f;  // 1/sqrt(128)
    float4* o4 = reinterpret_cast<float4*>(out);
    sfor<4>([&](auto F_) {
      constexpr int f = F_.value;
      const float4 a = acc[f];
      const float4 c2 = Red[(t & 127) * 4 + f + 512];
      o4[(size_t)n * NC + fquad * 4 + f] = make_float4(
          (a.x + c2.x) * s4, (a.y + c2.y) * s4,
          (a.z + c2.z) * s4, (a.w + c2.w) * s4);
    });
  }
}

// ------------------------------- launcher --------------------------------------
extern "C" void kernel_launch(void* const* d_in, const int* in_sizes, int n_in,
                              void* d_out, int out_size, void* d_ws, size_t ws_size,
                              hipStream_t stream) {
  const float* nf  = (const float*)d_in[0];
  const float* w1  = (const float*)d_in[1];
  const float* w2  = (const float*)d_in[2];
  const float* w3  = (const float*)d_in[3];
  const float* lw0 = (const float*)d_in[4];
  const float* lw1 = (const float*)d_in[5];
  const int*   spc = (const int*)  d_in[6];
  float* out = (float*)d_out;
  float4* Bws = (float4*)d_ws;   // [N][C] float4 = 8 MB
  (void)ws_size; (void)in_sizes; (void)n_in; (void)out_size;

  hipLaunchKernelGGL(epb_basis, dim3(NN / 4), dim3(256), 0, stream,
                     nf, w1, w2, w3, spc, Bws);
  hipLaunchKernelGGL(epb_linear, dim3(NN / 16 * 4), dim3(256), 0, stream,
                     Bws, (const float4*)lw0, (const float4*)lw1, out);
}

// Round 9
// 98.042 us; speedup vs baseline: 1.3716x; 1.3716x over previous
//
#include <hip/hip_runtime.h>
#include <utility>

// EquivariantProductBasisBlock (MACE-style) for gfx950 — round 20.
// R19 measurement: linear standalone 50.6us @ VALUBusy 12.9%; with R11 (26),
// R18 (25), fused-B (25): every linear structure runs ~13% VALU util.
// Arithmetic: 25us = 60k cyc/wave over ~64 load-groups ~= 900 cyc/event =
// HBM/L3-class latency on every W-load group, serialized group-after-group
// (loads of group k+1 only issue after consume of k frees regs). At 4
// waves/SIMD, 128-512 cyc work per 900 cyc stall = 13-25% util. Explains
// R11/R12/R14/R18/R19 with one mechanism.
// R20 = exact R12 (best, 100.05us) with ONE change: phase B inner loop ->
// 4 batches of 8 iters; each batch issues all 16 W float4 loads into a reg
// array back-to-back, then consumes (LDS B reads + 256 FMA). One latency
// per batch amortized over 512 cyc FMA (x4 waves). VGPR spike +64 -> peak
// ~105-115 <= 128 so occupancy stays 4 waves/SIMD (m69 cliff at 128).
// Math order unchanged -> absmax unchanged.
// Predict: VGPR ~100-115, kernel 45.7 -> ~28-33us, dur ~85-89.

#define NN 4096
#define NC 128
#define NE 10

typedef float v2f __attribute__((ext_vector_type(2)));

__device__ __forceinline__ v2f ld2(const float* p) {
  return *reinterpret_cast<const v2f*>(p);
}
__device__ __forceinline__ v2f cfma(float c, v2f x, v2f a) {  // a += c*x (splat c)
  v2f cc = {c, c};
  return __builtin_elementwise_fma(cc, x, a);
}
__device__ __forceinline__ v2f vfma(v2f w, v2f x, v2f a) {    // a += w*x
  return __builtin_elementwise_fma(w, x, a);
}

// ---------------------------- static_for ---------------------------------------
template<typename F, int... Is>
__device__ __forceinline__ void sfor_impl(F&& f, std::integer_sequence<int, Is...>) {
  (f(std::integral_constant<int, Is>{}), ...);
}
template<int N, typename F>
__device__ __forceinline__ void sfor(F&& f) {
  sfor_impl((F&&)f, std::make_integer_sequence<int, N>{});
}

// ---------------------------- CG metadata (constexpr) --------------------------
constexpr int T_L1c[19]  = {0,0,0,1,1,1,1,1,1,1,2,2,2,2,2,2,2,2,3};
constexpr int T_L2c[19]  = {0,1,2,0,1,1,1,2,2,2,0,1,1,1,2,2,2,2,2};
constexpr int T_L3c[19]  = {0,1,2,1,0,1,2,1,2,3,2,1,2,3,0,1,2,3,1};
constexpr int T_OFFc[19] = {0,1,10,35,44,53,80,125,170,245,350,375,420,495,600,625,700,825,1000};
constexpr int AOFFc[3]   = {0,1,4};

constexpr int P2U_L1c[7]  = {0,0,1,1,1,2,2};
constexpr int P2U_L2c[7]  = {0,1,1,1,2,2,2};
constexpr int P2U_LOc[7]  = {0,1,0,1,1,0,1};
constexpr int P2U_TBLc[7] = {0,1,4,5,7,14,15};
constexpr int P2U_WAc[7]  = {0,1,3,4,5,7,8};
constexpr int P2U_WBc[7]  = {-1,2,-1,-1,6,-1,-1};

constexpr int K_L1c[18]  = {0,0,0,1,1,1,1,1,1,1,2,2,2,2,2,2,2,2};
constexpr int K_L2c[18]  = {0,1,2,0,1,1,1,2,2,2,0,1,1,1,2,2,2,2};
constexpr int K_L12c[18] = {0,1,2,1,0,1,2,1,2,3,2,1,2,3,0,1,2,3};

constexpr int   TT_CANONc[18] = {0,1,2,1,4,5,6,7,8,9,2,7,8,9,14,15,16,17};
constexpr float TT_SGNc[18]   = {1,1,1,1,1,1,1,1,1,1,1,1,-1,1,1,1,1,1};
constexpr int CANONc[13] = {0,1,2,4,5,6,7,8,9,14,15,16,17};
constexpr int CONS2c[13] = {-1,3,10,-1,-1,-1,11,12,13,-1,-1,-1,-1};

constexpr int P3_STARTc[19] = {0,2,6,9,13,15,19,22,26,29,30,33,37,40,41,43,47,50,51};
constexpr int P3_L3c[51] = {
  0,1,  0,1,1,2,  1,2,2,  0,1,1,2,  0,1,  0,1,1,2,  1,2,2,  0,1,1,2,  1,2,2,
  2,  1,2,2,  0,1,1,2,  1,2,2,  2,  0,1,  0,1,1,2,  1,2,2,  2 };
constexpr int P3_LOc[51] = {
  0,1,  1,0,1,1,  1,0,1,  1,0,1,1,  0,1,  1,0,1,1,  1,0,1,  1,0,1,1,  1,0,1,
  1,  1,0,1,  1,0,1,1,  1,0,1,  1,  0,1,  1,0,1,1,  1,0,1,  1 };
constexpr int P3_TBLc[51] = {
  0,1,  3,4,5,7,  11,14,15,  3,4,5,7,  0,1,  3,4,5,7,  11,14,15,  3,4,5,7,
  11,14,15,  18,  11,14,15,  3,4,5,7,  11,14,15,  18,  0,1,  3,4,5,7,
  11,14,15,  18 };

// ---------------------------- constexpr CG computation -------------------------
constexpr double cfact(int n) { double r = 1.0; for (int i = 2; i <= n; ++i) r *= i; return r; }
constexpr double csqrt(double x) {
  if (x <= 0.0) return 0.0;
  double r = x > 1.0 ? x : 1.0;
  for (int i = 0; i < 64; ++i) r = 0.5 * (r + x / r);
  return r;
}
constexpr double su2cg(int j1, int m1, int j2, int m2, int j3, int m3) {
  if (m3 != m1 + m2) return 0.0;
  int vmin = -j1 + j2 + m3; if (-j1 + m1 > vmin) vmin = -j1 + m1; if (vmin < 0) vmin = 0;
  int vmax = j2 + j3 + m1; if (j3 - j1 + j2 < vmax) vmax = j3 - j1 + j2; if (j3 + m3 < vmax) vmax = j3 + m3;
  double C = csqrt((2.0 * j3 + 1.0)
                   * cfact(j3 + j1 - j2) * cfact(j3 - j1 + j2) * cfact(j1 + j2 - j3)
                   * cfact(j3 + m3) * cfact(j3 - m3)
                   / (cfact(j1 + j2 + j3 + 1) * cfact(j1 - m1) * cfact(j1 + m1)
                      * cfact(j2 - m2) * cfact(j2 + m2)));
  double S = 0.0;
  for (int v = vmin; v <= vmax; ++v) {
    double sgn = ((v + j2 + m2) & 1) ? -1.0 : 1.0;
    S += sgn * cfact(j2 + j3 + m1 - v) * cfact(j1 - m1 + v)
         / (cfact(v) * cfact(j3 - j1 + j2 - v) * cfact(j3 + m3 - v) * cfact(v + j1 - j2 - m3));
  }
  return C * S;
}

struct Cx { double re, im; };
constexpr Cx cxmul(Cx a, Cx b) { return Cx{a.re * b.re - a.im * b.im, a.re * b.im + a.im * b.re}; }
struct Row { int cnt; int col[2]; Cx v[2]; };

constexpr Row c2r_row(int l, int r) {
  Row out{0, {0, 0}, {{0, 0}, {0, 0}}};
  constexpr double is2 = 0.70710678118654752440;
  const int m = r - l;
  if (m < 0) {
    out.cnt = 2;
    out.col[0] = l - m; out.v[0] = Cx{is2, 0.0};
    out.col[1] = l + m; out.v[1] = Cx{0.0, -is2};
  } else if (m == 0) {
    out.cnt = 1; out.col[0] = l; out.v[0] = Cx{1.0, 0.0};
  } else {
    const double sgn = (m & 1) ? -1.0 : 1.0;
    out.cnt = 2;
    out.col[0] = l + m; out.v[0] = Cx{sgn * is2, 0.0};
    out.col[1] = l - m; out.v[1] = Cx{0.0, sgn * is2};
  }
  const int ph = l & 3;
  for (int a = 0; a < out.cnt; ++a) {
    Cx v = out.v[a];
    out.v[a] = (ph == 0) ? v
             : (ph == 1) ? Cx{v.im, -v.re}
             : (ph == 2) ? Cx{-v.re, -v.im}
                         : Cx{-v.im, v.re};
  }
  return out;
}

struct CGAll { float v[1105]; };
constexpr CGAll make_cg() {
  CGAll R{};
  for (int t = 0; t < 19; ++t) {
    const int l1 = T_L1c[t], l2 = T_L2c[t], l3 = T_L3c[t], off = T_OFFc[t];
    const int d1 = 2 * l1 + 1, d2 = 2 * l2 + 1, d3 = 2 * l3 + 1;
    double tmp[175] = {};
    for (int i = 0; i < d1; ++i) {
      const int m1 = i - l1;
      const Row r1 = c2r_row(l1, i);
      for (int k = 0; k < d2; ++k) {
        const int m2 = k - l2, m3 = m1 + m2;
        if (m3 < -l3 || m3 > l3) continue;
        const double cc = su2cg(l1, m1, l2, m2, l3, m3);
        if (cc == 0.0) continue;
        const Row r2 = c2r_row(l2, k);
        const Row r3 = c2r_row(l3, m3 + l3);
        for (int a = 0; a < r1.cnt; ++a)
          for (int b = 0; b < r2.cnt; ++b) {
            const Cx q12 = cxmul(r1.v[a], r2.v[b]);
            for (int cdx = 0; cdx < r3.cnt; ++cdx) {
              const double re = q12.re * r3.v[cdx].re + q12.im * r3.v[cdx].im;
              tmp[(r1.col[a] * d2 + r2.col[b]) * d3 + r3.col[cdx]] += re * cc;
            }
          }
      }
    }
    const int sz = d1 * d2 * d3;
    for (int e = 0; e < sz; ++e) R.v[off + e] = (float)tmp[e];
  }
  return R;
}
constexpr CGAll CG_ALL = make_cg();

constexpr bool check_cg_sym() {
  for (int t = 0; t < 18; ++t) {
    const int tc = TT_CANONc[t];
    if (tc == t) continue;
    const int l1 = K_L1c[t], l2 = K_L2c[t], l12 = K_L12c[t];
    const int d1 = 2*l1+1, d2 = 2*l2+1, d12 = 2*l12+1;
    for (int i = 0; i < d1; ++i)
      for (int j = 0; j < d2; ++j)
        for (int k = 0; k < d12; ++k) {
          float a = CG_ALL.v[T_OFFc[t]  + (i*d2 + j)*d12 + k];
          float b = TT_SGNc[t] * CG_ALL.v[T_OFFc[tc] + (j*d1 + i)*d12 + k];
          float d = a - b; if (d < 0) d = -d;
          if (d > 1e-5f) return false;
        }
  }
  return true;
}
static_assert(check_cg_sym(), "CG exchange symmetry violated");

// ============================ fused basis + linear kernel ======================
// Block = 4 nodes x 256 threads (R12 structure). Phase A (basis): wave nl
// owns node nb+nl, lanes own channel pairs; B -> 8KB LDS. Phase B (linear):
// thread = (f-quad q, node-pair dup, 32-ch chunk = wave); W loads batched
// 16-at-a-time into regs (one latency per batch); partials -> 32KB Red;
// 4-way tree-reduce + coalesced float4 store.
__global__ __launch_bounds__(256) void epb_fused(
    const float*  __restrict__ nf,      // [N, C, 9]
    const float*  __restrict__ w1,      // [E, 2, C]
    const float*  __restrict__ w2,      // [E, 9, C]
    const float*  __restrict__ w3,      // [E, 51, C]
    const float4* __restrict__ lw0_4,   // [C, F/4]
    const float4* __restrict__ lw1_4,   // [C, F/4]
    const int*    __restrict__ species, // [N]
    float* __restrict__ out)            // [N, F, 4]
{
  __shared__ float4 Bsh[4 * NC];        //  8 KB  [node][channel] (m0..m3)
  __shared__ float4 Red[16 * NC];       // 32 KB  [node*4+f_local][chunk*32+q]

  const int t  = threadIdx.x;
  const int nb = blockIdx.x * 4;

  // ---------------- phase A: basis (math unchanged from R9) ----------------
  {
    const int nl = t >> 6;               // wave-uniform node
    const int c0 = (t & 63) * 2;         // channel pair
    const int n  = nb + nl;
    const int s  = species[n];

    const float* ap = nf + ((size_t)n * NC + c0) * 9;
    v2f A[9];
    sfor<9>([&](auto I) { A[I.value] = v2f{ap[I.value], ap[I.value + 9]}; });

    const float* w1p = w1 + (size_t)s * 2  * NC + c0;
    const float* w2p = w2 + (size_t)s * 9  * NC + c0;
    const float* w3p = w3 + (size_t)s * 51 * NC + c0;

    v2f B[4];
    {
      const v2f wa = ld2(w1p), wb = ld2(w1p + NC);
      B[0] = wa * A[0];
      B[1] = wb * A[1];
      B[2] = wb * A[2];
      B[3] = wb * A[3];
    }

    sfor<7>([&](auto P) {
      constexpr int p  = P.value;
      constexpr int l1 = P2U_L1c[p], l2 = P2U_L2c[p], lo = P2U_LOc[p];
      constexpr int d1 = 2*l1+1, d2 = 2*l2+1, dl = 2*lo+1;
      constexpr int off = T_OFFc[P2U_TBLc[p]];
      v2f w = ld2(w2p + P2U_WAc[p] * NC);
      if constexpr (P2U_WBc[p] >= 0) w = w + ld2(w2p + P2U_WBc[p] * NC);
      sfor<dl>([&](auto Kk) {
        constexpr int k = Kk.value;
        v2f v = {0.f, 0.f};
        sfor<d1>([&](auto I) {
          sfor<d2>([&](auto J) {
            constexpr float cgc = CG_ALL.v[off + (I.value * d2 + J.value) * dl + k];
            if constexpr (cgc != 0.0f) {
              constexpr int ia = AOFFc[l1] + I.value, ja = AOFFc[l2] + J.value;
              constexpr int x = ia < ja ? ia : ja, y = ia < ja ? ja : ia;
              v = cfma(cgc, A[x] * A[y], v);
            }
          });
        });
        B[lo + k] = vfma(w, v, B[lo + k]);
      });
    });

    sfor<13>([&](auto CI) {
      constexpr int tk  = CANONc[CI.value];
      constexpr int l1  = K_L1c[tk], l2 = K_L2c[tk], l12 = K_L12c[tk];
      constexpr int d1  = 2*l1+1, d2 = 2*l2+1, d12 = 2*l12+1;
      constexpr int off = T_OFFc[tk];
      v2f tt[d12];
      sfor<d12>([&](auto Kk) {
        constexpr int k = Kk.value;
        v2f v = {0.f, 0.f};
        sfor<d1>([&](auto I) {
          sfor<d2>([&](auto J) {
            constexpr float cgc = CG_ALL.v[off + (I.value * d2 + J.value) * d12 + k];
            if constexpr (cgc != 0.0f) {
              constexpr int ia = AOFFc[l1] + I.value, ja = AOFFc[l2] + J.value;
              constexpr int x = ia < ja ? ia : ja, y = ia < ja ? ja : ia;
              v = cfma(cgc, A[x] * A[y], v);
            }
          });
        });
        tt[k] = v;
      });

      auto consume = [&](auto TK, auto SG) {
        constexpr int tkey = TK.value;
        constexpr float sgn = (float)SG.value;
        constexpr int pcnt = P3_STARTc[tkey + 1] - P3_STARTc[tkey];
        sfor<pcnt>([&](auto PP) {
          constexpr int p  = P3_STARTc[tkey] + PP.value;
          constexpr int l3 = P3_L3c[p], lo = P3_LOc[p];
          constexpr int d3 = 2*l3+1, dl = 2*lo+1;
          constexpr int off2 = T_OFFc[P3_TBLc[p]];
          const v2f w = ld2(w3p + p * NC);
          sfor<dl>([&](auto M) {
            v2f v = {0.f, 0.f};
            sfor<d12>([&](auto Kk) {
              sfor<d3>([&](auto J) {
                constexpr float cgc = sgn * CG_ALL.v[off2 + (Kk.value * d3 + J.value) * dl + M.value];
                if constexpr (cgc != 0.0f)
                  v = cfma(cgc, tt[Kk.value] * A[AOFFc[l3] + J.value], v);
              });
            });
            B[lo + M.value] = vfma(w, v, B[lo + M.value]);
          });
        });
      };
      consume(std::integral_constant<int, tk>{}, std::integral_constant<int, 1>{});
      constexpr int td = CONS2c[CI.value];
      if constexpr (td >= 0)
        consume(std::integral_constant<int, td>{},
                std::integral_constant<int, (int)TT_SGNc[td]>{});
    });

    Bsh[nl * NC + c0]     = make_float4(B[0].x, B[1].x, B[2].x, B[3].x);
    Bsh[nl * NC + c0 + 1] = make_float4(B[0].y, B[1].y, B[2].y, B[3].y);
  }
  __syncthreads();

  // ---------------- phase B: equivariant linear (batched W prefetch) -------
  // thread -> (q = f-quad 0..31, dup = node-pair 0/1, wv = 32-ch chunk 0..3)
  const int q   = t & 31;
  const int dup = (t >> 5) & 1;
  const int wv  = t >> 6;
  const int n0  = dup * 2;

  float4 acc[2][4] = {};                 // [node-in-pair][f_local], comps in float4

  const float4* w0c = lw0_4 + (size_t)(wv * 32) * 32 + q;
  const float4* w1c = lw1_4 + (size_t)(wv * 32) * 32 + q;
  const float4* bp0 = &Bsh[ n0      * NC + wv * 32];
  const float4* bp1 = &Bsh[(n0 + 1) * NC + wv * 32];

  // 4 batches of 8 c-iters. Each batch issues its 16 independent W loads
  // back-to-back into registers (ONE memory latency per batch, amortized
  // over 512 cycles of FMA), then consumes with LDS broadcast reads.
  #pragma unroll 1
  for (int g = 0; g < 4; ++g) {
    float4 wA[8], wB[8];
    sfor<8>([&](auto I) {
      wA[I.value] = w0c[(size_t)(g * 8 + I.value) * 32];
      wB[I.value] = w1c[(size_t)(g * 8 + I.value) * 32];
    });
    sfor<8>([&](auto I) {
      const int i = g * 8 + I.value;
      const float4 wa = wA[I.value];
      const float4 wb = wB[I.value];
      const float4 ba = bp0[i];            // 2-addr broadcast ds_read
      const float4 bb = bp1[i];
#define FQ(f, waf, wbf) \
      acc[0][f].x = fmaf(ba.x, waf, acc[0][f].x); \
      acc[0][f].y = fmaf(ba.y, wbf, acc[0][f].y); \
      acc[0][f].z = fmaf(ba.z, wbf, acc[0][f].z); \
      acc[0][f].w = fmaf(ba.w, wbf, acc[0][f].w); \
      acc[1][f].x = fmaf(bb.x, waf, acc[1][f].x); \
      acc[1][f].y = fmaf(bb.y, wbf, acc[1][f].y); \
      acc[1][f].z = fmaf(bb.z, wbf, acc[1][f].z); \
      acc[1][f].w = fmaf(bb.w, wbf, acc[1][f].w);
      FQ(0, wa.x, wb.x)
      FQ(1, wa.y, wb.y)
      FQ(2, wa.z, wb.z)
      FQ(3, wa.w, wb.w)
#undef FQ
    });
  }

  // partials to Red: unique slot per (node, f_local, chunk, q); per-instr lane
  // addresses are 16B-consecutive within each half-wave, halves 16KB apart ->
  // 2-way bank alias (free).
  sfor<2>([&](auto NN_) {
    sfor<4>([&](auto F_) {
      Red[((n0 + NN_.value) * 4 + F_.value) * NC + wv * 32 + q] = acc[NN_.value][F_.value];
    });
  });
  __syncthreads();

  // 4-way tree reduce + scale + coalesced store (2 float4 outputs per thread)
  const float s4 = 0.08838834764831845f;  // 1/sqrt(128)
  float4* o4 = reinterpret_cast<float4*>(out);
  sfor<2>([&](auto O_) {
    const int oid = 2 * t + O_.value;     // 0..511 = 4 nodes x 128 features
    const int n   = oid >> 7;
    const int rem = oid & 127;            // feature index
    const int row = (n * 4 + (rem & 3)) * NC + (rem >> 2);
    const float4 r0 = Red[row];
    const float4 r1 = Red[row + 32];
    const float4 r2 = Red[row + 64];
    const float4 r3 = Red[row + 96];
    o4[(size_t)(nb + n) * NC + rem] = make_float4(
        ((r0.x + r1.x) + (r2.x + r3.x)) * s4,
        ((r0.y + r1.y) + (r2.y + r3.y)) * s4,
        ((r0.z + r1.z) + (r2.z + r3.z)) * s4,
        ((r0.w + r1.w) + (r2.w + r3.w)) * s4);
  });
}

// ------------------------------- launcher --------------------------------------
extern "C" void kernel_launch(void* const* d_in, const int* in_sizes, int n_in,
                              void* d_out, int out_size, void* d_ws, size_t ws_size,
                              hipStream_t stream) {
  const float* nf  = (const float*)d_in[0];
  const float* w1  = (const float*)d_in[1];
  const float* w2  = (const float*)d_in[2];
  const float* w3  = (const float*)d_in[3];
  const float* lw0 = (const float*)d_in[4];
  const float* lw1 = (const float*)d_in[5];
  const int*   spc = (const int*)  d_in[6];
  float* out = (float*)d_out;
  (void)d_ws; (void)ws_size; (void)in_sizes; (void)n_in; (void)out_size;

  hipLaunchKernelGGL(epb_fused, dim3(NN / 4), dim3(256), 0, stream,
                     nf, w1, w2, w3, (const float4*)lw0, (const float4*)lw1,
                     spc, out);
}